// Round 8
// baseline (494.610 us; speedup 1.0000x reference)
//
#include <hip/hip_runtime.h>

// SingleLSTM: B=32768, T=28, INPUT=28, HIDDEN=128, LABELS=10, fp32.
// R8 = R7 + AGPR-pin for Wh + launch_bounds(512,2).
// Key insight: occupancy is gated by TOTAL unified regs (arch + AGPR).
// Ladder observed: (512,2)->128, (512,3)->85, (512,4)->64 ARCH cap; with
// Wh(64)+temps the total was ~150 -> 3 waves/SIMD -> 1 block/CU (8-wave
// granularity). Fix: pin Wh fragments to AGPR class via empty asm "+a";
// gfx950 MFMA reads A/B straight from AGPRs (AV operand class), so no
// per-use moves. Target: 64 AGPR + ~62 arch <= 128 total -> 4 waves/SIMD
// -> 2 resident blocks/CU, out-of-phase (activation VALU + LDS of one
// block hides under the other's MFMA phase).
// Structure (unchanged from R7): fp16 datapath; 16 rows/block, 2048
// blocks; wave owns 16 hidden cols x 4 gates; per-lane c/h update; one
// barrier/step; Wx in LDS, x staged via LDS double-buffer. W/bias
// pre-scaled by {-L2E, 2L2E, -L2E, -L2E}; c kept in 2*L2E units.

typedef _Float16 f16x8 __attribute__((ext_vector_type(8)));
typedef float f32x4 __attribute__((ext_vector_type(4)));

#define HSTRIDE 136    // f16 elems; 272B row
#define WXSTRIDE 40    // f16 elems; 80B row
#define L2E 1.44269504f

__global__ __launch_bounds__(512, 2)
void lstm_r8(const float* __restrict__ x,      // [B][28][28]
             const float* __restrict__ W,      // [156][512]
             const float* __restrict__ b,      // [512]
             const float* __restrict__ Wfc,    // [128][10]
             const float* __restrict__ bfc,    // [10]
             float* __restrict__ out)          // [B][10]
{
    __shared__ __align__(16) _Float16 h_s[2][16 * HSTRIDE];   // 8704 B
    __shared__ __align__(16) _Float16 xs[2][512];             // 2048 B
    __shared__ __align__(16) _Float16 wxt[512 * WXSTRIDE];    // 40960 B

    const int tid  = threadIdx.x;
    const int wave = tid >> 6;
    const int lane = tid & 63;
    const int m16  = lane & 15;
    const int quad = lane >> 4;
    const int rbase = blockIdx.x * 16;
    const int hc = wave * 16 + m16;     // this lane's hidden column

    // ---- zero h buf0 and both xs buffers ----
    for (int i = tid; i < 16 * HSTRIDE; i += 512) h_s[0][i] = (_Float16)0.0f;
    xs[0][tid] = (_Float16)0.0f;
    xs[1][tid] = (_Float16)0.0f;

    // ---- stage Wx into LDS, transposed [col][k], pre-scaled ----
    {
        const int col = tid;             // one col per thread
        const int g = col >> 7;
        const float sc = (g == 1) ? 2.0f * L2E : -L2E;
        #pragma unroll 4
        for (int k = 0; k < 32; k++)
            wxt[col * WXSTRIDE + k] = (k < 28) ? (_Float16)(sc * W[k * 512 + col])
                                               : (_Float16)0.0f;
    }

    // barrier between zero-init and the permuted t=0 staging writes (R6 race)
    __syncthreads();

    // ---- Wh fragments (fp16, pre-scaled), B-layout, PINNED TO AGPRs ----
    // lane holds B[k=quad*8+j][col]; 16 frags x 4 regs = 64 AGPRs.
    f16x8 Wh[4][4];     // [ks][gate]
    float bias[4];
    #pragma unroll
    for (int g = 0; g < 4; g++) {
        const int col = g * 128 + wave * 16 + m16;
        const float sc = (g == 1) ? 2.0f * L2E : -L2E;
        bias[g] = sc * (b[col] + (g == 2 ? 1.0f : 0.0f));   // FORGET_BIAS folded
        #pragma unroll
        for (int ks = 0; ks < 4; ks++) {
            f16x8 h8;
            #pragma unroll
            for (int j = 0; j < 8; j++)
                h8[j] = (_Float16)(sc * W[(28 + ks * 32 + quad * 8 + j) * 512 + col]);
            __asm__("" : "+a"(h8));   // pin to AGPR class; MFMA reads it directly
            Wh[ks][g] = h8;
        }
    }

    // ---- per-thread x staging slot (16 rows x 28 k = 448 elems) ----
    const bool sact = tid < 448;
    const int srow = tid / 28, sk = tid % 28;
    const int soff = (sk >> 3) * 128 + srow * 8 + (sk & 7);
    const float* xp = x + (size_t)(rbase + srow) * 784 + sk;
    if (sact) xs[0][soff] = (_Float16)(*xp);
    __syncthreads();

    float creg[4] = {0.0f, 0.0f, 0.0f, 0.0f};
    const int foff   = quad * 128 + m16 * 8;                   // xs A-frag offset
    const int wxoff0 = (wave * 16 + m16) * WXSTRIDE + quad * 8;
    const int hoff0  = m16 * HSTRIDE + quad * 8;

    int buf = 0;
    for (int t = 0; t < 28; t++) {
        const int nb = buf ^ 1;

        // stage x for t+1 (read after the NEXT barrier -> race-free)
        if (t < 27 && sact) xs[nb][soff] = (_Float16)(xp[(t + 1) * 28]);

        // ---- gates for 16 rows: acc[g][r], row = quad*4+r, col = hc ----
        f32x4 acc[4];
        #pragma unroll
        for (int g = 0; g < 4; g++)
            acc[g] = (f32x4){bias[g], bias[g], bias[g], bias[g]};

        f16x8 ax = *(const f16x8*)(&xs[buf][foff]);
        #pragma unroll
        for (int g = 0; g < 4; g++) {
            f16x8 wxf = *(const f16x8*)(&wxt[g * 128 * WXSTRIDE + wxoff0]);
            acc[g] = __builtin_amdgcn_mfma_f32_16x16x32_f16(ax, wxf, acc[g], 0, 0, 0);
        }
        #pragma unroll
        for (int ks = 0; ks < 4; ks++) {
            f16x8 ah = *(const f16x8*)(&h_s[buf][hoff0 + ks * 32]);
            #pragma unroll
            for (int g = 0; g < 4; g++)
                acc[g] = __builtin_amdgcn_mfma_f32_16x16x32_f16(ah, Wh[ks][g], acc[g], 0, 0, 0);
        }

        // ---- per-lane c/h update (gates pre-scaled; c in 2*L2E units) ----
        #pragma unroll
        for (int r = 0; r < 4; r++) {
            float ei  = __builtin_amdgcn_exp2f(acc[0][r]);   // e^-i
            float e2j = __builtin_amdgcn_exp2f(acc[1][r]);   // e^2j
            float ef  = __builtin_amdgcn_exp2f(acc[2][r]);   // e^-(f+1)
            float eo  = __builtin_amdgcn_exp2f(acc[3][r]);   // e^-o
            float A  = 1.0f + ei;
            float Bv = e2j + 1.0f;
            float C  = 1.0f + ef;
            float AB = A * Bv;
            float rP = __builtin_amdgcn_rcpf(AB * C);        // 1/(A*B*C)
            float num = __builtin_fmaf(e2j, 2.0f * L2E, -2.0f * L2E);
            float cn = __builtin_fmaf(creg[r], AB * rP, num * (C * rP));
            creg[r] = cn;
            float e2c = __builtin_amdgcn_exp2f(cn);          // e^2c
            float rQ  = __builtin_amdgcn_rcpf((e2c + 1.0f) * (1.0f + eo));
            float hv  = (e2c - 1.0f) * rQ;
            h_s[nb][(quad * 4 + r) * HSTRIDE + hc] = (_Float16)hv;
        }
        __syncthreads();
        buf = nb;
    }

    // ---- FC epilogue: logits = h @ Wfc + bfc ----
    if (tid < 160) {
        const int row = tid / 10, lab = tid % 10;
        float acc = bfc[lab];
        #pragma unroll 8
        for (int k = 0; k < 128; k++)
            acc += (float)h_s[buf][row * HSTRIDE + k] * Wfc[k * 10 + lab];
        out[(size_t)(rbase + row) * 10 + lab] = acc;
    }
}

extern "C" void kernel_launch(void* const* d_in, const int* in_sizes, int n_in,
                              void* d_out, int out_size, void* d_ws, size_t ws_size,
                              hipStream_t stream) {
    const float* x   = (const float*)d_in[0];
    const float* W   = (const float*)d_in[1];
    const float* b   = (const float*)d_in[2];
    const float* Wfc = (const float*)d_in[3];
    const float* bfc = (const float*)d_in[4];
    float* out = (float*)d_out;

    const int B = in_sizes[0] / (28 * 28);   // 32768
    const int blocks = B / 16;               // 2048
    lstm_r8<<<blocks, 512, 0, stream>>>(x, W, b, Wfc, bfc, out);
}

// Round 9
// 383.480 us; speedup vs baseline: 1.2898x; 1.2898x over previous
//
#include <hip/hip_runtime.h>

// SingleLSTM: B=32768, T=28, INPUT=28, HIDDEN=128, LABELS=10, fp32.
// R9: attack the per-step stall (R7: ~4050 cyc/block-step vs ~1450 of pipe
// work). (1) Staging split: global x load at step START (reg), LDS write at
// step END -> vmcnt wait lands after ~1000 cyc of MFMA/VALU instead of
// stalling the wave before the first MFMA. (2) 32 rows/block, two 16-row
// tiles software-pipelined: MFMA(A), MFMA(B), act(A) [overlaps B's MFMA
// execution], act(B). (3) Wx in regs (16), Wh left to compiler (lands in
// AGPRs per R7 evidence; pinning changed nothing in R8). One barrier/step.
// fp16 datapath; W/bias pre-scaled by {-L2E, 2L2E, -L2E, -L2E}; c in
// 2*L2E units (absmax 0.0039 across R4-R8 with this math).

typedef _Float16 f16x8 __attribute__((ext_vector_type(8)));
typedef float f32x4 __attribute__((ext_vector_type(4)));

#define HSTRIDE 136    // f16 elems; 272B row = 17*16B: b128-aligned, 2-way banks
#define L2E 1.44269504f

__global__ __launch_bounds__(512, 2)
void lstm_r9(const float* __restrict__ x,      // [B][28][28]
             const float* __restrict__ W,      // [156][512]
             const float* __restrict__ b,      // [512]
             const float* __restrict__ Wfc,    // [128][10]
             const float* __restrict__ bfc,    // [10]
             float* __restrict__ out)          // [B][10]
{
    __shared__ __align__(16) _Float16 h_s[2][32 * HSTRIDE];   // 17408 B
    __shared__ __align__(16) _Float16 xs[2][2][512];          // 4096 B

    const int tid  = threadIdx.x;
    const int wave = tid >> 6;
    const int lane = tid & 63;
    const int m16  = lane & 15;
    const int quad = lane >> 4;
    const int rbase = blockIdx.x * 32;
    const int hc = wave * 16 + m16;     // this lane's hidden column

    // ---- zero h buf0 and xs (k>=28 slots must stay 0 forever) ----
    for (int i = tid; i < 32 * HSTRIDE; i += 512) h_s[0][i] = (_Float16)0.0f;
    for (int i = tid; i < 2 * 2 * 512; i += 512) ((_Float16*)xs)[i] = (_Float16)0.0f;

    // ---- W fragments (fp16, pre-scaled), B-layout: lane holds B[k=quad*8+j][col]
    f16x8 Wx[4];        // x rows (k<28, rest 0) -- 16 arch regs
    f16x8 Wh[4][4];     // [ks][gate] -- compiler places (AGPRs per R7)
    float bias[4];
    #pragma unroll
    for (int g = 0; g < 4; g++) {
        const int col = g * 128 + wave * 16 + m16;
        const float sc = (g == 1) ? 2.0f * L2E : -L2E;
        bias[g] = sc * (b[col] + (g == 2 ? 1.0f : 0.0f));   // FORGET_BIAS folded
        f16x8 w8;
        #pragma unroll
        for (int j = 0; j < 8; j++) {
            int kk = quad * 8 + j;
            w8[j] = (kk < 28) ? (_Float16)(sc * W[kk * 512 + col]) : (_Float16)0.0f;
        }
        Wx[g] = w8;
        #pragma unroll
        for (int ks = 0; ks < 4; ks++) {
            f16x8 h8;
            #pragma unroll
            for (int j = 0; j < 8; j++)
                h8[j] = (_Float16)(sc * W[(28 + ks * 32 + quad * 8 + j) * 512 + col]);
            Wh[ks][g] = h8;
        }
    }

    // barrier: zero-init must complete before the permuted t=0 staging (R6 race)
    __syncthreads();

    // ---- per-thread x staging slots (32 rows x 28 k = 896 elems) ----
    const int srow  = tid / 28, sk = tid % 28;
    const int smt   = srow >> 4;
    const int soff  = (sk >> 3) * 128 + (srow & 15) * 8 + (sk & 7);
    const int sidx2 = tid + 512;
    const int srow2 = sidx2 / 28, sk2 = sidx2 % 28;
    const int smt2  = srow2 >> 4;
    const int soff2 = (sk2 >> 3) * 128 + (srow2 & 15) * 8 + (sk2 & 7);
    const bool sact2 = tid < 384;
    const float* xp  = x + (size_t)(rbase + srow)  * 784 + sk;
    const float* xp2 = x + (size_t)(rbase + srow2) * 784 + sk2;

    // stage x for t=0
    xs[0][smt][soff] = (_Float16)(*xp);
    if (sact2) xs[0][smt2][soff2] = (_Float16)(*xp2);
    __syncthreads();

    float creg[8];
    #pragma unroll
    for (int i = 0; i < 8; i++) creg[i] = 0.0f;

    const int foff = quad * 128 + m16 * 8;   // xs A-frag offset

    int buf = 0;
    for (int t = 0; t < 28; t++) {
        const int nb = buf ^ 1;

        // ---- EARLY: issue global loads for t+1 into regs (no wait here) ----
        float xv0 = 0.0f, xv1 = 0.0f;
        if (t < 27) {
            xv0 = xp[(t + 1) * 28];
            if (sact2) xv1 = xp2[(t + 1) * 28];
        }

        // ---- A-frags for both row tiles ----
        f16x8 ax[2];
        ax[0] = *(const f16x8*)(&xs[buf][0][foff]);
        ax[1] = *(const f16x8*)(&xs[buf][1][foff]);

        f32x4 acc[2][4];
        #pragma unroll
        for (int mt = 0; mt < 2; mt++)
            #pragma unroll
            for (int g = 0; g < 4; g++)
                acc[mt][g] = (f32x4){bias[g], bias[g], bias[g], bias[g]};

        // ---- MFMA chain, tile A then tile B (B's chain covers A's act) ----
        #pragma unroll
        for (int mt = 0; mt < 2; mt++) {
            #pragma unroll
            for (int g = 0; g < 4; g++)
                acc[mt][g] = __builtin_amdgcn_mfma_f32_16x16x32_f16(ax[mt], Wx[g], acc[mt][g], 0, 0, 0);
            #pragma unroll
            for (int ks = 0; ks < 4; ks++) {
                f16x8 ah = *(const f16x8*)(&h_s[buf][(mt * 16 + m16) * HSTRIDE + ks * 32 + quad * 8]);
                #pragma unroll
                for (int g = 0; g < 4; g++)
                    acc[mt][g] = __builtin_amdgcn_mfma_f32_16x16x32_f16(ah, Wh[ks][g], acc[mt][g], 0, 0, 0);
            }
        }

        // ---- activations: tile A first (overlaps tile B's MFMAs) ----
        #pragma unroll
        for (int mt = 0; mt < 2; mt++) {
            #pragma unroll
            for (int r = 0; r < 4; r++) {
                float ei  = __builtin_amdgcn_exp2f(acc[mt][0][r]);   // e^-i
                float e2j = __builtin_amdgcn_exp2f(acc[mt][1][r]);   // e^2j
                float ef  = __builtin_amdgcn_exp2f(acc[mt][2][r]);   // e^-(f+1)
                float eo  = __builtin_amdgcn_exp2f(acc[mt][3][r]);   // e^-o
                float A   = 1.0f + ei;
                float Bv  = e2j + 1.0f;
                float C   = 1.0f + ef;
                float AB  = A * Bv;
                float rP  = __builtin_amdgcn_rcpf(AB * C);
                float num = __builtin_fmaf(e2j, 2.0f * L2E, -2.0f * L2E);
                float cn  = __builtin_fmaf(creg[mt * 4 + r], AB * rP, num * (C * rP));
                creg[mt * 4 + r] = cn;
                float e2c = __builtin_amdgcn_exp2f(cn);              // e^2c
                float rQ  = __builtin_amdgcn_rcpf((e2c + 1.0f) * (1.0f + eo));
                float hv  = (e2c - 1.0f) * rQ;
                h_s[nb][(mt * 16 + quad * 4 + r) * HSTRIDE + hc] = (_Float16)hv;
            }
        }

        // ---- LATE: stage x(t+1) to LDS (vmcnt long since satisfied) ----
        if (t < 27) {
            xs[nb][smt][soff] = (_Float16)xv0;
            if (sact2) xs[nb][smt2][soff2] = (_Float16)xv1;
        }
        __syncthreads();
        buf = nb;
    }

    // ---- FC epilogue: logits = h @ Wfc + bfc ----
    if (tid < 320) {
        const int row = tid / 10, lab = tid % 10;
        float acc = bfc[lab];
        #pragma unroll 8
        for (int k = 0; k < 128; k++)
            acc += (float)h_s[buf][row * HSTRIDE + k] * Wfc[k * 10 + lab];
        out[(size_t)(rbase + row) * 10 + lab] = acc;
    }
}

extern "C" void kernel_launch(void* const* d_in, const int* in_sizes, int n_in,
                              void* d_out, int out_size, void* d_ws, size_t ws_size,
                              hipStream_t stream) {
    const float* x   = (const float*)d_in[0];
    const float* W   = (const float*)d_in[1];
    const float* b   = (const float*)d_in[2];
    const float* Wfc = (const float*)d_in[3];
    const float* bfc = (const float*)d_in[4];
    float* out = (float*)d_out;

    const int B = in_sizes[0] / (28 * 28);   // 32768
    const int blocks = B / 32;               // 1024
    lstm_r9<<<blocks, 512, 0, stream>>>(x, W, b, Wfc, bfc, out);
}

// Round 10
// 347.562 us; speedup vs baseline: 1.4231x; 1.1033x over previous
//
#include <hip/hip_runtime.h>

// SingleLSTM: B=32768, T=28, INPUT=28, HIDDEN=128, LABELS=10, fp32.
// R10 = R9 scaled to 64 rows/block (512 blocks): four 16-row tiles between
// each barrier -> 56 barrier-steps/CU (was 112), 2x work per barrier; tile
// k+1's ds_read+MFMA chain overlaps tile k's activation VALU. Early global
// x loads (step start) / late LDS writes (step end) as R9. Wh lands in
// AGPRs (R7/R8 evidence), Wx+temps in ~110 arch VGPRs -> no spill at
// (512,2). fp16 datapath; W/bias pre-scaled {-L2E, 2L2E, -L2E, -L2E}; c in
// 2*L2E units (absmax 0.0039 stable across R4-R9).

typedef _Float16 f16x8 __attribute__((ext_vector_type(8)));
typedef float f32x4 __attribute__((ext_vector_type(4)));

#define HSTRIDE 136    // f16 elems; 272B row = 17*16B (b128-aligned rows)
#define L2E 1.44269504f

__global__ __launch_bounds__(512, 2)
void lstm_r10(const float* __restrict__ x,      // [B][28][28]
              const float* __restrict__ W,      // [156][512]
              const float* __restrict__ b,      // [512]
              const float* __restrict__ Wfc,    // [128][10]
              const float* __restrict__ bfc,    // [10]
              float* __restrict__ out)          // [B][10]
{
    __shared__ __align__(16) _Float16 h_s[2][64 * HSTRIDE];   // 34816 B
    __shared__ __align__(16) _Float16 xs[2][4][512];          // 8192 B

    const int tid  = threadIdx.x;
    const int wave = tid >> 6;
    const int lane = tid & 63;
    const int m16  = lane & 15;
    const int quad = lane >> 4;
    const int rbase = blockIdx.x * 64;
    const int hc = wave * 16 + m16;     // this lane's hidden column

    // ---- zero h buf0 and xs (k>=28 slots must stay 0 forever) ----
    for (int i = tid; i < 64 * HSTRIDE; i += 512) h_s[0][i] = (_Float16)0.0f;
    for (int i = tid; i < 2 * 4 * 512; i += 512) ((_Float16*)xs)[i] = (_Float16)0.0f;

    // ---- W fragments (fp16, pre-scaled), B-layout: lane holds B[k=quad*8+j][col]
    f16x8 Wx[4];        // x rows (k<28, rest 0) -- 16 arch regs
    f16x8 Wh[4][4];     // [ks][gate] -- compiler places in AGPRs
    float bias[4];
    #pragma unroll
    for (int g = 0; g < 4; g++) {
        const int col = g * 128 + wave * 16 + m16;
        const float sc = (g == 1) ? 2.0f * L2E : -L2E;
        bias[g] = sc * (b[col] + (g == 2 ? 1.0f : 0.0f));   // FORGET_BIAS folded
        f16x8 w8;
        #pragma unroll
        for (int j = 0; j < 8; j++) {
            int kk = quad * 8 + j;
            w8[j] = (kk < 28) ? (_Float16)(sc * W[kk * 512 + col]) : (_Float16)0.0f;
        }
        Wx[g] = w8;
        #pragma unroll
        for (int ks = 0; ks < 4; ks++) {
            f16x8 h8;
            #pragma unroll
            for (int j = 0; j < 8; j++)
                h8[j] = (_Float16)(sc * W[(28 + ks * 32 + quad * 8 + j) * 512 + col]);
            Wh[ks][g] = h8;
        }
    }

    // barrier: zero-init must complete before the permuted t=0 staging (R6 race)
    __syncthreads();

    // ---- per-thread x staging slots: 64 rows x 28 k = 1792 elems, 4 slots ----
    // slot e handles idx = e*512 + tid; e<3 always active, e=3 iff tid<256
    int ssmt[4], ssoff[4];
    const float* sxp[4];
    #pragma unroll
    for (int e = 0; e < 4; e++) {
        const int idx = e * 512 + tid;
        const int srow = idx / 28, sk = idx % 28;
        ssmt[e]  = srow >> 4;
        ssoff[e] = (sk >> 3) * 128 + (srow & 15) * 8 + (sk & 7);
        sxp[e]   = x + (size_t)(rbase + srow) * 784 + sk;
    }
    const bool sact3 = tid < 256;

    // stage x for t=0
    #pragma unroll
    for (int e = 0; e < 3; e++) xs[0][ssmt[e]][ssoff[e]] = (_Float16)(*sxp[e]);
    if (sact3) xs[0][ssmt[3]][ssoff[3]] = (_Float16)(*sxp[3]);
    __syncthreads();

    float creg[16];
    #pragma unroll
    for (int i = 0; i < 16; i++) creg[i] = 0.0f;

    const int foff = quad * 128 + m16 * 8;   // xs A-frag offset

    int buf = 0;
    for (int t = 0; t < 28; t++) {
        const int nb = buf ^ 1;

        // ---- EARLY: issue global loads for t+1 (no wait until step end) ----
        float xv[4] = {0.f, 0.f, 0.f, 0.f};
        if (t < 27) {
            #pragma unroll
            for (int e = 0; e < 3; e++) xv[e] = sxp[e][(t + 1) * 28];
            if (sact3) xv[3] = sxp[3][(t + 1) * 28];
        }

        // ---- four 16-row tiles, sequential acc, overlapping chains ----
        #pragma unroll
        for (int mt = 0; mt < 4; mt++) {
            f32x4 acc[4];
            #pragma unroll
            for (int g = 0; g < 4; g++)
                acc[g] = (f32x4){bias[g], bias[g], bias[g], bias[g]};

            f16x8 ax = *(const f16x8*)(&xs[buf][mt][foff]);
            #pragma unroll
            for (int g = 0; g < 4; g++)
                acc[g] = __builtin_amdgcn_mfma_f32_16x16x32_f16(ax, Wx[g], acc[g], 0, 0, 0);
            #pragma unroll
            for (int ks = 0; ks < 4; ks++) {
                f16x8 ah = *(const f16x8*)(&h_s[buf][(mt * 16 + m16) * HSTRIDE + ks * 32 + quad * 8]);
                #pragma unroll
                for (int g = 0; g < 4; g++)
                    acc[g] = __builtin_amdgcn_mfma_f32_16x16x32_f16(ah, Wh[ks][g], acc[g], 0, 0, 0);
            }

            // activation for this tile (overlaps next tile's MFMA chain)
            #pragma unroll
            for (int r = 0; r < 4; r++) {
                float ei  = __builtin_amdgcn_exp2f(acc[0][r]);   // e^-i
                float e2j = __builtin_amdgcn_exp2f(acc[1][r]);   // e^2j
                float ef  = __builtin_amdgcn_exp2f(acc[2][r]);   // e^-(f+1)
                float eo  = __builtin_amdgcn_exp2f(acc[3][r]);   // e^-o
                float A   = 1.0f + ei;
                float Bv  = e2j + 1.0f;
                float C   = 1.0f + ef;
                float AB  = A * Bv;
                float rP  = __builtin_amdgcn_rcpf(AB * C);
                float num = __builtin_fmaf(e2j, 2.0f * L2E, -2.0f * L2E);
                float cn  = __builtin_fmaf(creg[mt * 4 + r], AB * rP, num * (C * rP));
                creg[mt * 4 + r] = cn;
                float e2c = __builtin_amdgcn_exp2f(cn);          // e^2c
                float rQ  = __builtin_amdgcn_rcpf((e2c + 1.0f) * (1.0f + eo));
                float hv  = (e2c - 1.0f) * rQ;
                h_s[nb][(mt * 16 + quad * 4 + r) * HSTRIDE + hc] = (_Float16)hv;
            }
        }

        // ---- LATE: stage x(t+1) to LDS (vmcnt satisfied long ago) ----
        if (t < 27) {
            #pragma unroll
            for (int e = 0; e < 3; e++) xs[nb][ssmt[e]][ssoff[e]] = (_Float16)xv[e];
            if (sact3) xs[nb][ssmt[3]][ssoff[3]] = (_Float16)xv[3];
        }
        __syncthreads();
        buf = nb;
    }

    // ---- FC epilogue: logits = h @ Wfc + bfc (640 outputs) ----
    for (int i = tid; i < 640; i += 512) {
        const int row = i / 10, lab = i % 10;
        float acc = bfc[lab];
        #pragma unroll 8
        for (int k = 0; k < 128; k++)
            acc += (float)h_s[buf][row * HSTRIDE + k] * Wfc[k * 10 + lab];
        out[(size_t)(rbase + row) * 10 + lab] = acc;
    }
}

extern "C" void kernel_launch(void* const* d_in, const int* in_sizes, int n_in,
                              void* d_out, int out_size, void* d_ws, size_t ws_size,
                              hipStream_t stream) {
    const float* x   = (const float*)d_in[0];
    const float* W   = (const float*)d_in[1];
    const float* b   = (const float*)d_in[2];
    const float* Wfc = (const float*)d_in[3];
    const float* bfc = (const float*)d_in[4];
    float* out = (float*)d_out;

    const int B = in_sizes[0] / (28 * 28);   // 32768
    const int blocks = B / 64;               // 512
    lstm_r10<<<blocks, 512, 0, stream>>>(x, W, b, Wfc, bfc, out);
}